// Round 4
// baseline (345.850 us; speedup 1.0000x reference)
//
#include <hip/hip_runtime.h>

// Fused attention fwd: x@Wqkv -> RoPE -> causal flash attn (bf16 MFMA) -> @Wout
// B=2 T=2048 D=1024 H=16 DH=64
#define B_ 2
#define T_ 2048
#define D_ 1024
#define H_ 16
#define DH_ 64
#define N3_ 3072
#define M_ 4096

typedef __attribute__((ext_vector_type(8))) short short8;      // 8 bf16 (4 VGPR) MFMA A/B frag
typedef __attribute__((ext_vector_type(4))) float f32x4;       // MFMA C/D frag
typedef __attribute__((ext_vector_type(4))) unsigned short ushort4v;

__device__ __forceinline__ unsigned short f2bf(float f) {
  union { float f; unsigned u; } v; v.f = f;
  unsigned r = v.u + 0x7FFFu + ((v.u >> 16) & 1u);   // RNE, inputs finite
  return (unsigned short)(r >> 16);
}
__device__ __forceinline__ float bf2f(unsigned short u) {
  union { unsigned u; float f; } v; v.u = ((unsigned)u) << 16;
  return v.f;
}

// ---------- f32 -> bf16 bulk convert (4 elems/thread, exact grid) ----------
__global__ __launch_bounds__(256)
void k_cvt(const float* __restrict__ in, unsigned short* __restrict__ out) {
  int i = (blockIdx.x * 256 + threadIdx.x) * 4;
  f32x4 v = *(const f32x4*)&in[i];
  ushort4v o;
  o[0] = f2bf(v[0]); o[1] = f2bf(v[1]); o[2] = f2bf(v[2]); o[3] = f2bf(v[3]);
  *(ushort4v*)&out[i] = o;
}

// ---------- transpose f32 [R][C] -> bf16 [C][R] (64x64 LDS tile) ----------
__global__ __launch_bounds__(256)
void k_transpose(const float* __restrict__ in, unsigned short* __restrict__ out,
                 int R, int C) {
  __shared__ float tile[64][65];
  int c0 = blockIdx.x * 64, r0 = blockIdx.y * 64;
  int tx = threadIdx.x & 63, ty = threadIdx.x >> 6;
#pragma unroll
  for (int i = 0; i < 64; i += 4)
    tile[ty + i][tx] = in[(size_t)(r0 + ty + i) * C + c0 + tx];
  __syncthreads();
#pragma unroll
  for (int i = 0; i < 64; i += 4)
    out[(size_t)(c0 + ty + i) * R + r0 + tx] = f2bf(tile[tx][ty + i]);
}

// ---------- GEMM: C[M][N] = A[M][K] @ Bt[N][K]^T, bf16 in, OUT_T out ----------
// 128x128 tile, BK=64, 4 waves (2x2), 4x4 16x16x32 MFMA frags per wave.
template <typename OUT_T>
__global__ __launch_bounds__(256)
void k_gemm_bt(const unsigned short* __restrict__ A, const unsigned short* __restrict__ Bt,
               OUT_T* __restrict__ C, int Mx, int Nx, int Kx) {
  __shared__ __align__(16) unsigned short As[128 * 64];
  __shared__ __align__(16) unsigned short Bs[128 * 64];
  const int tid = threadIdx.x;
  const int lane = tid & 63;
  const int l15 = lane & 15, lg = lane >> 4;
  const int wid = tid >> 6;
  const int wr = wid >> 1, wc = wid & 1;
  const int m0 = blockIdx.y * 128, n0 = blockIdx.x * 128;

  const f32x4 zero4 = {0.f, 0.f, 0.f, 0.f};
  f32x4 acc[4][4];
#pragma unroll
  for (int mi = 0; mi < 4; ++mi)
#pragma unroll
    for (int ni = 0; ni < 4; ++ni) acc[mi][ni] = zero4;

  for (int k0 = 0; k0 < Kx; k0 += 64) {
#pragma unroll
    for (int c = tid; c < 1024; c += 256) {   // 1024 chunks of 16B per tile pair
      int r = c >> 3, cc = (c & 7) << 3;
      *(short8*)&As[r * 64 + cc] = *(const short8*)&A[(size_t)(m0 + r) * Kx + k0 + cc];
      *(short8*)&Bs[r * 64 + cc] = *(const short8*)&Bt[(size_t)(n0 + r) * Kx + k0 + cc];
    }
    __syncthreads();
#pragma unroll
    for (int kk = 0; kk < 2; ++kk) {
      short8 af[4], bfr[4];
#pragma unroll
      for (int mi = 0; mi < 4; ++mi)
        af[mi] = *(const short8*)&As[(wr * 64 + mi * 16 + l15) * 64 + kk * 32 + lg * 8];
#pragma unroll
      for (int ni = 0; ni < 4; ++ni)
        bfr[ni] = *(const short8*)&Bs[(wc * 64 + ni * 16 + l15) * 64 + kk * 32 + lg * 8];
#pragma unroll
      for (int mi = 0; mi < 4; ++mi)
#pragma unroll
        for (int ni = 0; ni < 4; ++ni)
          acc[mi][ni] = __builtin_amdgcn_mfma_f32_16x16x32_bf16(af[mi], bfr[ni], acc[mi][ni], 0, 0, 0);
    }
    __syncthreads();
  }
  // C/D layout: reg j -> row (lg*4+j), col l15  [verified m89/m91]
#pragma unroll
  for (int mi = 0; mi < 4; ++mi)
#pragma unroll
    for (int ni = 0; ni < 4; ++ni)
#pragma unroll
      for (int j = 0; j < 4; ++j) {
        int row = m0 + wr * 64 + mi * 16 + lg * 4 + j;
        int col = n0 + wc * 64 + ni * 16 + l15;
        float v = acc[mi][ni][j];
        if constexpr (sizeof(OUT_T) == 2) C[(size_t)row * Nx + col] = f2bf(v);
        else                              C[(size_t)row * Nx + col] = v;
      }
}

// ---------- RoPE + layout: qkv[4096][3072] -> Q,K [BH][T][DH] (Q pre-scaled 1/8), V^T [BH][DH][T] ----------
__global__ __launch_bounds__(256)
void k_rope(const unsigned short* __restrict__ qkv, const float* __restrict__ cosT,
            const float* __restrict__ sinT, unsigned short* __restrict__ Q,
            unsigned short* __restrict__ K, unsigned short* __restrict__ Vt) {
  int idx = blockIdx.x * 256 + threadIdx.x;        // B*H*T*32 threads
  int dh = idx & 31;
  int t  = (idx >> 5) & (T_ - 1);
  int h  = (idx >> 16) & (H_ - 1);
  int b  = idx >> 20;
  size_t base = (size_t)(b * T_ + t) * N3_;
  int c0 = h * DH_ + dh;
  float q1 = bf2f(qkv[base + c0]);
  float q2 = bf2f(qkv[base + c0 + 32]);
  float k1 = bf2f(qkv[base + D_ + c0]);
  float k2 = bf2f(qkv[base + D_ + c0 + 32]);
  float cs = cosT[t * 32 + dh], sn = sinT[t * 32 + dh];
  size_t qkb = ((size_t)(b * H_ + h) * T_ + t) * DH_ + dh;
  Q[qkb]      = f2bf((q1 * cs - q2 * sn) * 0.125f);   // attn scale folded into Q
  Q[qkb + 32] = f2bf((q2 * cs + q1 * sn) * 0.125f);
  K[qkb]      = f2bf(k1 * cs - k2 * sn);
  K[qkb + 32] = f2bf(k2 * cs + k1 * sn);
  size_t vb = ((size_t)(b * H_ + h) * DH_ + dh) * T_ + t;
  Vt[vb]           = qkv[base + 2 * D_ + c0];
  Vt[vb + 32 * T_] = qkv[base + 2 * D_ + c0 + 32];
}

// ---------- causal flash attention ----------
// 4 independent waves/block; each wave owns 16 q-rows, loops KV in 32-tiles.
// S^T = K·Q^T so each lane holds one q-row (q=lane&15) -> softmax reduce = 2 shfl_xor.
// P bounced via padded LDS into PV A-frag; V^T gives contiguous PV B-frags.
__global__ __launch_bounds__(256)
void k_attn(const unsigned short* __restrict__ Q, const unsigned short* __restrict__ K,
            const unsigned short* __restrict__ Vt, unsigned short* __restrict__ O) {
  __shared__ __align__(16) unsigned short Pl[4][16][40];   // per-wave P tile, padded stride
  const int tid = threadIdx.x;
  const int wid = tid >> 6, lane = tid & 63;
  const int l15 = lane & 15, lg = lane >> 4;
  const int qb = 31 - (blockIdx.x & 31);      // reversed: longest jobs first
  const int hb = blockIdx.x >> 5;             // b*H + h
  const int q0 = qb * 64 + wid * 16;
  const size_t hbase = (size_t)hb * T_ * DH_;
  const unsigned short* Qh = Q + hbase;
  const unsigned short* Kh = K + hbase;
  const unsigned short* Vh = Vt + hbase;      // [DH][T]
  unsigned short* Pw = &Pl[wid][0][0];

  // Q^T B-frags, hoisted (b[i] = Q[q0+l15][kk*32+lg*8+i])
  short8 bq0 = *(const short8*)&Qh[(q0 + l15) * DH_ + lg * 8];
  short8 bq1 = *(const short8*)&Qh[(q0 + l15) * DH_ + 32 + lg * 8];

  const f32x4 zero4 = {0.f, 0.f, 0.f, 0.f};
  f32x4 accO[4];
#pragma unroll
  for (int nb = 0; nb < 4; ++nb) accO[nb] = zero4;
  float m_run = -INFINITY, l_run = 0.f;
  const int qg = q0 + l15;
  const int kend = q0 + 16;

  for (int kt = 0; kt < kend; kt += 32) {
    // S^T tiles: c0 = k rows [kt,kt+16), c1 = [kt+16,kt+32)
    f32x4 c0 = zero4, c1 = zero4;
    short8 a;
    a = *(const short8*)&Kh[(kt + l15) * DH_ + lg * 8];
    c0 = __builtin_amdgcn_mfma_f32_16x16x32_bf16(a, bq0, c0, 0, 0, 0);
    a = *(const short8*)&Kh[(kt + l15) * DH_ + 32 + lg * 8];
    c0 = __builtin_amdgcn_mfma_f32_16x16x32_bf16(a, bq1, c0, 0, 0, 0);
    a = *(const short8*)&Kh[(kt + 16 + l15) * DH_ + lg * 8];
    c1 = __builtin_amdgcn_mfma_f32_16x16x32_bf16(a, bq0, c1, 0, 0, 0);
    a = *(const short8*)&Kh[(kt + 16 + l15) * DH_ + 32 + lg * 8];
    c1 = __builtin_amdgcn_mfma_f32_16x16x32_bf16(a, bq1, c1, 0, 0, 0);

    // lane holds S[q=q0+l15][k = kt + lg*4 + j (+16)]
    float s[8];
#pragma unroll
    for (int j = 0; j < 4; ++j) { s[j] = c0[j]; s[4 + j] = c1[j]; }
    // Causal mask needed iff this tile's max k (kt+31) exceeds the wave's
    // min q (q0). NOTE: previous condition (kt+31 > q0+15) skipped the
    // boundary tile for waves with q0%32==16 -> future-key leak (absmax 1.03).
    if (kt + 31 > q0) {
      int kb0 = kt + lg * 4;
#pragma unroll
      for (int j = 0; j < 4; ++j) {
        if (kb0 + j > qg)      s[j]     = -INFINITY;
        if (kb0 + 16 + j > qg) s[4 + j] = -INFINITY;
      }
    }
    float pm = s[0];
#pragma unroll
    for (int j = 1; j < 8; ++j) pm = fmaxf(pm, s[j]);
    pm = fmaxf(pm, __shfl_xor(pm, 16));
    pm = fmaxf(pm, __shfl_xor(pm, 32));
    float m_new = fmaxf(m_run, pm);
    float alpha = __expf(m_run - m_new);      // first tile: exp(-inf)=0
    float p[8], psum = 0.f;
#pragma unroll
    for (int j = 0; j < 8; ++j) { p[j] = __expf(s[j] - m_new); psum += p[j]; }
    psum += __shfl_xor(psum, 16);
    psum += __shfl_xor(psum, 32);
    l_run = l_run * alpha + psum;
    m_run = m_new;

    // P -> LDS (bf16) at P[q_local=l15][k_local], row stride 40
#pragma unroll
    for (int j = 0; j < 4; ++j) {
      Pw[l15 * 40 + lg * 4 + j]      = f2bf(p[j]);
      Pw[l15 * 40 + 16 + lg * 4 + j] = f2bf(p[4 + j]);
    }
    // per-output-row alpha (accO row = lg*4+j)
    float aj[4];
#pragma unroll
    for (int j = 0; j < 4; ++j) aj[j] = __shfl(alpha, lg * 4 + j);
    // PV: A-frag from LDS P, B-frag from V^T (contiguous in t)
    short8 pa = *(const short8*)&Pw[l15 * 40 + lg * 8];
#pragma unroll
    for (int nb = 0; nb < 4; ++nb) {
#pragma unroll
      for (int j = 0; j < 4; ++j) accO[nb][j] *= aj[j];
      short8 vb = *(const short8*)&Vh[(size_t)(nb * 16 + l15) * T_ + kt + lg * 8];
      accO[nb] = __builtin_amdgcn_mfma_f32_16x16x32_bf16(pa, vb, accO[nb], 0, 0, 0);
    }
  }
  // epilogue: /l, write O[(b*T+t)][h*64+dh] bf16
  float lj[4];
#pragma unroll
  for (int j = 0; j < 4; ++j) lj[j] = 1.f / __shfl(l_run, lg * 4 + j);
  int b = hb >> 4, h = hb & 15;
#pragma unroll
  for (int nb = 0; nb < 4; ++nb)
#pragma unroll
    for (int j = 0; j < 4; ++j) {
      int t = q0 + lg * 4 + j;
      O[(size_t)(b * T_ + t) * D_ + h * DH_ + nb * 16 + l15] = f2bf(accO[nb][j] * lj[j]);
    }
}

extern "C" void kernel_launch(void* const* d_in, const int* in_sizes, int n_in,
                              void* d_out, int out_size, void* d_ws, size_t ws_size,
                              hipStream_t stream) {
  const float* x    = (const float*)d_in[0];
  const float* Wqkv = (const float*)d_in[1];
  const float* Wout = (const float*)d_in[2];
  const float* cosT = (const float*)d_in[3];
  const float* sinT = (const float*)d_in[4];
  // d_in[5] = mask (unused; causal handled analytically)
  float* out = (float*)d_out;
  char* ws = (char*)d_ws;
  // ws layout (bytes): 64 MB total
  unsigned short* Xb     = (unsigned short*)(ws);              //  8.0 MB  x bf16 [4096][1024]
  unsigned short* Wqkv_t = (unsigned short*)(ws + 8388608);    //  6.0 MB  Wqkv^T bf16 [3072][1024]
  unsigned short* Wout_t = (unsigned short*)(ws + 14680064);   //  2.0 MB  Wout^T bf16 [1024][1024]
  unsigned short* QKVb   = (unsigned short*)(ws + 16777216);   // 24.0 MB  qkv bf16 [4096][3072]
  unsigned short* Qb     = (unsigned short*)(ws + 41943040);   //  8.0 MB  [BH][T][DH]
  unsigned short* Kb     = (unsigned short*)(ws + 50331648);   //  8.0 MB  [BH][T][DH]
  unsigned short* Vt     = (unsigned short*)(ws + 58720256);   //  8.0 MB  [BH][DH][T]
  unsigned short* Ob     = QKVb;                               // reuse (qkv dead after rope)

  k_cvt<<<4096, 256, 0, stream>>>(x, Xb);
  k_transpose<<<dim3(48, 16), 256, 0, stream>>>(Wqkv, Wqkv_t, 1024, 3072);
  k_transpose<<<dim3(16, 16), 256, 0, stream>>>(Wout, Wout_t, 1024, 1024);
  k_gemm_bt<unsigned short><<<dim3(24, 32), 256, 0, stream>>>(Xb, Wqkv_t, QKVb, 4096, 3072, 1024);
  k_rope<<<8192, 256, 0, stream>>>(QKVb, cosT, sinT, Qb, Kb, Vt);
  k_attn<<<1024, 256, 0, stream>>>(Qb, Kb, Vt, Ob);
  k_gemm_bt<float><<<dim3(8, 32), 256, 0, stream>>>(Ob, Wout_t, out, 4096, 1024, 1024);
}

// Round 5
// 212.169 us; speedup vs baseline: 1.6301x; 1.6301x over previous
//
#include <hip/hip_runtime.h>

// Fused attention fwd: x@Wqkv -> RoPE -> causal flash attn (bf16 MFMA) -> @Wout
// B=2 T=2048 D=1024 H=16 DH=64
#define B_ 2
#define T_ 2048
#define D_ 1024
#define H_ 16
#define DH_ 64
#define N3_ 3072
#define M_ 4096

typedef __attribute__((ext_vector_type(8))) short short8;      // 8 bf16 (4 VGPR) MFMA A/B frag
typedef __attribute__((ext_vector_type(4))) float f32x4;       // MFMA C/D frag
typedef __attribute__((ext_vector_type(4))) unsigned short ushort4v;

__device__ __forceinline__ unsigned short f2bf(float f) {
  union { float f; unsigned u; } v; v.f = f;
  unsigned r = v.u + 0x7FFFu + ((v.u >> 16) & 1u);   // RNE, inputs finite
  return (unsigned short)(r >> 16);
}
__device__ __forceinline__ float bf2f(unsigned short u) {
  union { unsigned u; float f; } v; v.u = ((unsigned)u) << 16;
  return v.f;
}

// async global->LDS, 16B per lane; LDS dest is WAVE-UNIFORM base + lane*16 [m97/m104]
__device__ __forceinline__ void gload_lds16(const unsigned short* g, unsigned short* l) {
  __builtin_amdgcn_global_load_lds((const __attribute__((address_space(1))) void*)g,
                                   (__attribute__((address_space(3))) void*)l, 16, 0, 0);
}

// ---------- f32 -> bf16 bulk convert (4 elems/thread, exact grid) ----------
__global__ __launch_bounds__(256)
void k_cvt(const float* __restrict__ in, unsigned short* __restrict__ out) {
  int i = (blockIdx.x * 256 + threadIdx.x) * 4;
  f32x4 v = *(const f32x4*)&in[i];
  ushort4v o;
  o[0] = f2bf(v[0]); o[1] = f2bf(v[1]); o[2] = f2bf(v[2]); o[3] = f2bf(v[3]);
  *(ushort4v*)&out[i] = o;
}

// ---------- transpose f32 [R][C] -> bf16 [C][R] (64x64 LDS tile) ----------
__global__ __launch_bounds__(256)
void k_transpose(const float* __restrict__ in, unsigned short* __restrict__ out,
                 int R, int C) {
  __shared__ float tile[64][65];
  int c0 = blockIdx.x * 64, r0 = blockIdx.y * 64;
  int tx = threadIdx.x & 63, ty = threadIdx.x >> 6;
#pragma unroll
  for (int i = 0; i < 64; i += 4)
    tile[ty + i][tx] = in[(size_t)(r0 + ty + i) * C + c0 + tx];
  __syncthreads();
#pragma unroll
  for (int i = 0; i < 64; i += 4)
    out[(size_t)(c0 + ty + i) * R + r0 + tx] = f2bf(tile[tx][ty + i]);
}

// ---------- GEMM: C[M][N] = A[M][K] @ Bt[N][K]^T, bf16 in, OUT_T out ----------
// 128x128 tile, BK=64, 4 waves (2x2), 4x4 16x16x32 MFMA frags per wave.
template <typename OUT_T>
__global__ __launch_bounds__(256)
void k_gemm_bt(const unsigned short* __restrict__ A, const unsigned short* __restrict__ Bt,
               OUT_T* __restrict__ C, int Mx, int Nx, int Kx) {
  __shared__ __align__(16) unsigned short As[128 * 64];
  __shared__ __align__(16) unsigned short Bs[128 * 64];
  const int tid = threadIdx.x;
  const int lane = tid & 63;
  const int l15 = lane & 15, lg = lane >> 4;
  const int wid = tid >> 6;
  const int wr = wid >> 1, wc = wid & 1;
  const int m0 = blockIdx.y * 128, n0 = blockIdx.x * 128;

  const f32x4 zero4 = {0.f, 0.f, 0.f, 0.f};
  f32x4 acc[4][4];
#pragma unroll
  for (int mi = 0; mi < 4; ++mi)
#pragma unroll
    for (int ni = 0; ni < 4; ++ni) acc[mi][ni] = zero4;

  for (int k0 = 0; k0 < Kx; k0 += 64) {
#pragma unroll
    for (int c = tid; c < 1024; c += 256) {   // 1024 chunks of 16B per tile pair
      int r = c >> 3, cc = (c & 7) << 3;
      *(short8*)&As[r * 64 + cc] = *(const short8*)&A[(size_t)(m0 + r) * Kx + k0 + cc];
      *(short8*)&Bs[r * 64 + cc] = *(const short8*)&Bt[(size_t)(n0 + r) * Kx + k0 + cc];
    }
    __syncthreads();
#pragma unroll
    for (int kk = 0; kk < 2; ++kk) {
      short8 af[4], bfr[4];
#pragma unroll
      for (int mi = 0; mi < 4; ++mi)
        af[mi] = *(const short8*)&As[(wr * 64 + mi * 16 + l15) * 64 + kk * 32 + lg * 8];
#pragma unroll
      for (int ni = 0; ni < 4; ++ni)
        bfr[ni] = *(const short8*)&Bs[(wc * 64 + ni * 16 + l15) * 64 + kk * 32 + lg * 8];
#pragma unroll
      for (int mi = 0; mi < 4; ++mi)
#pragma unroll
        for (int ni = 0; ni < 4; ++ni)
          acc[mi][ni] = __builtin_amdgcn_mfma_f32_16x16x32_bf16(af[mi], bfr[ni], acc[mi][ni], 0, 0, 0);
    }
    __syncthreads();
  }
  // C/D layout: reg j -> row (lg*4+j), col l15  [verified m89/m91]
#pragma unroll
  for (int mi = 0; mi < 4; ++mi)
#pragma unroll
    for (int ni = 0; ni < 4; ++ni)
#pragma unroll
      for (int j = 0; j < 4; ++j) {
        int row = m0 + wr * 64 + mi * 16 + lg * 4 + j;
        int col = n0 + wc * 64 + ni * 16 + l15;
        float v = acc[mi][ni][j];
        if constexpr (sizeof(OUT_T) == 2) C[(size_t)row * Nx + col] = f2bf(v);
        else                              C[(size_t)row * Nx + col] = v;
      }
}

// ---------- RoPE + layout: qkv[4096][3072] -> Q,K [BH][T][DH] (Q pre-scaled 1/8), V^T [BH][DH][T] ----------
__global__ __launch_bounds__(256)
void k_rope(const unsigned short* __restrict__ qkv, const float* __restrict__ cosT,
            const float* __restrict__ sinT, unsigned short* __restrict__ Q,
            unsigned short* __restrict__ K, unsigned short* __restrict__ Vt) {
  int idx = blockIdx.x * 256 + threadIdx.x;        // B*H*T*32 threads
  int dh = idx & 31;
  int t  = (idx >> 5) & (T_ - 1);
  int h  = (idx >> 16) & (H_ - 1);
  int b  = idx >> 20;
  size_t base = (size_t)(b * T_ + t) * N3_;
  int c0 = h * DH_ + dh;
  float q1 = bf2f(qkv[base + c0]);
  float q2 = bf2f(qkv[base + c0 + 32]);
  float k1 = bf2f(qkv[base + D_ + c0]);
  float k2 = bf2f(qkv[base + D_ + c0 + 32]);
  float cs = cosT[t * 32 + dh], sn = sinT[t * 32 + dh];
  size_t qkb = ((size_t)(b * H_ + h) * T_ + t) * DH_ + dh;
  Q[qkb]      = f2bf((q1 * cs - q2 * sn) * 0.125f);   // attn scale folded into Q
  Q[qkb + 32] = f2bf((q2 * cs + q1 * sn) * 0.125f);
  K[qkb]      = f2bf(k1 * cs - k2 * sn);
  K[qkb + 32] = f2bf(k2 * cs + k1 * sn);
  size_t vb = ((size_t)(b * H_ + h) * DH_ + dh) * T_ + t;
  Vt[vb]           = qkv[base + 2 * D_ + c0];
  Vt[vb + 32 * T_] = qkv[base + 2 * D_ + c0 + 32];
}

// ---------- causal flash attention (block-cooperative, LDS-staged KV) ----------
// Block = 4 waves x 16 q-rows = 64 q-rows. KV loop in 64-key tiles, double-buffered
// LDS staging via global_load_lds (linear dest + pre-swizzled global source; reads
// XOR the same swizzle back -> conflict-free ds_read_b128 [T2/m201 pattern]).
// S^T = K.Q^T so each lane owns one q-row; softmax reduce = 2 shfl_xor.
__global__ __launch_bounds__(256)
void k_attn(const unsigned short* __restrict__ Q, const unsigned short* __restrict__ K,
            const unsigned short* __restrict__ Vt, unsigned short* __restrict__ O) {
  __shared__ __align__(16) unsigned short Ks[2 * 64 * 64];   // [buf][r][chunk^(r&7)] 8KB/buf
  __shared__ __align__(16) unsigned short Vs[2 * 64 * 64];   // same, rows = dh
  __shared__ __align__(16) unsigned short Pl[4][16][40];     // per-wave P tile, padded
  const int tid = threadIdx.x;
  const int wid = tid >> 6, lane = tid & 63;
  const int l15 = lane & 15, lg = lane >> 4;
  const int l8 = lane >> 3, c8 = lane & 7;
  const int srcoff = (c8 ^ l8) << 3;          // swizzled source chunk (ushort units)
  const int qb = 31 - (blockIdx.x & 31);      // reversed: longest jobs first
  const int hb = blockIdx.x >> 5;             // b*H + h
  const int qblk = qb * 64;
  const int q0 = qblk + wid * 16;
  const size_t hbase = (size_t)hb * T_ * DH_;
  const unsigned short* Qh = Q + hbase;
  const unsigned short* Kh = K + hbase;
  const unsigned short* Vh = Vt + hbase;      // [DH][T]
  unsigned short* Pw = &Pl[wid][0][0];

  // Q^T B-frags, hoisted (b[i] = Q[q0+l15][kk*32+lg*8+i])
  short8 bq0 = *(const short8*)&Qh[(q0 + l15) * DH_ + lg * 8];
  short8 bq1 = *(const short8*)&Qh[(q0 + l15) * DH_ + 32 + lg * 8];

  const f32x4 zero4 = {0.f, 0.f, 0.f, 0.f};
  f32x4 accO[4];
#pragma unroll
  for (int nb = 0; nb < 4; ++nb) accO[nb] = zero4;
  float m_run = -INFINITY, l_run = 0.f;
  const int qg = q0 + l15;
  const int kend_w = q0 + 16;                 // wave's exclusive key bound
  const int kend_blk = qblk + 64;             // block's exclusive key bound

  // stage one 64-key K+V tile into buf: 16 chunks of 1KB, 4 per wave.
  // chunk ch covers rows ch*8..ch*8+7; lane l lands at row ch*8+l/8, col-chunk l%8;
  // source col-chunk is (l%8)^(l/8) == c ^ (r&7)  -> LDS[r][c] = X[r][c^(r&7)].
  auto stage = [&](int buf, int kt) {
    if (wid < 2) {
#pragma unroll
      for (int i = 0; i < 4; ++i) {
        int ch = wid * 4 + i;
        gload_lds16(&Kh[(size_t)(kt + ch * 8 + l8) * DH_ + srcoff],
                    &Ks[buf * 4096 + ch * 512]);
      }
    } else {
#pragma unroll
      for (int i = 0; i < 4; ++i) {
        int ch = (wid - 2) * 4 + i;
        gload_lds16(&Vh[(size_t)(ch * 8 + l8) * T_ + kt + srcoff],
                    &Vs[buf * 4096 + ch * 512]);
      }
    }
  };

  stage(0, 0);
  for (int kt = 0; kt < kend_blk; kt += 64) {
    const int cur = (kt >> 6) & 1;
    __syncthreads();                          // staging of cur landed; cur^1 free
    if (kt + 64 < kend_blk) stage(cur ^ 1, kt + 64);
    const unsigned short* Kb_ = &Ks[cur * 4096];
    const unsigned short* Vb_ = &Vs[cur * 4096];

#pragma unroll
    for (int ks = 0; ks < 64; ks += 32) {
      const int ko = kt + ks;                 // global key offset of this 32-sub-tile
      if (ko >= kend_w) break;                // wave-uniform

      // S^T tiles: c0 = k rows [ko,ko+16), c1 = [ko+16,ko+32). K read swizzled.
      f32x4 c0 = zero4, c1 = zero4;
      {
        int r = ks + l15;
        short8 a0 = *(const short8*)&Kb_[r * 64 + (((lg)     ^ (r & 7)) << 3)];
        short8 a1 = *(const short8*)&Kb_[r * 64 + (((4 + lg) ^ (r & 7)) << 3)];
        c0 = __builtin_amdgcn_mfma_f32_16x16x32_bf16(a0, bq0, c0, 0, 0, 0);
        c0 = __builtin_amdgcn_mfma_f32_16x16x32_bf16(a1, bq1, c0, 0, 0, 0);
        r = ks + 16 + l15;
        a0 = *(const short8*)&Kb_[r * 64 + (((lg)     ^ (r & 7)) << 3)];
        a1 = *(const short8*)&Kb_[r * 64 + (((4 + lg) ^ (r & 7)) << 3)];
        c1 = __builtin_amdgcn_mfma_f32_16x16x32_bf16(a0, bq0, c1, 0, 0, 0);
        c1 = __builtin_amdgcn_mfma_f32_16x16x32_bf16(a1, bq1, c1, 0, 0, 0);
      }

      // lane holds S[q=q0+l15][k = ko + lg*4 + j (+16)]
      float s[8];
#pragma unroll
      for (int j = 0; j < 4; ++j) { s[j] = c0[j]; s[4 + j] = c1[j]; }
      if (ko + 31 > q0) {                     // boundary tile: causal mask
        int kb0 = ko + lg * 4;
#pragma unroll
        for (int j = 0; j < 4; ++j) {
          if (kb0 + j > qg)      s[j]     = -INFINITY;
          if (kb0 + 16 + j > qg) s[4 + j] = -INFINITY;
        }
      }
      float pm = s[0];
#pragma unroll
      for (int j = 1; j < 8; ++j) pm = fmaxf(pm, s[j]);
      pm = fmaxf(pm, __shfl_xor(pm, 16));
      pm = fmaxf(pm, __shfl_xor(pm, 32));
      float m_new = fmaxf(m_run, pm);
      float alpha = __expf(m_run - m_new);    // first tile: exp(-inf)=0
      float p[8], psum = 0.f;
#pragma unroll
      for (int j = 0; j < 8; ++j) { p[j] = __expf(s[j] - m_new); psum += p[j]; }
      psum += __shfl_xor(psum, 16);
      psum += __shfl_xor(psum, 32);
      l_run = l_run * alpha + psum;
      m_run = m_new;

      // P -> LDS (bf16), packed 8B stores at P[q=l15][lg*4(+16)]
      {
        ushort4v pk0, pk1;
#pragma unroll
        for (int j = 0; j < 4; ++j) { pk0[j] = f2bf(p[j]); pk1[j] = f2bf(p[4 + j]); }
        *(ushort4v*)&Pw[l15 * 40 + lg * 4]      = pk0;
        *(ushort4v*)&Pw[l15 * 40 + 16 + lg * 4] = pk1;
      }
      // per-output-row alpha (accO row = lg*4+j)
      float aj[4];
#pragma unroll
      for (int j = 0; j < 4; ++j) aj[j] = __shfl(alpha, lg * 4 + j);
      // PV: A-frag from LDS P, B-frag from swizzled V tile (rows = dh)
      short8 pa = *(const short8*)&Pw[l15 * 40 + lg * 8];
#pragma unroll
      for (int nb = 0; nb < 4; ++nb) {
#pragma unroll
        for (int j = 0; j < 4; ++j) accO[nb][j] *= aj[j];
        int r = nb * 16 + l15;
        short8 vb = *(const short8*)&Vb_[r * 64 + ((((ks >> 3) + lg) ^ (r & 7)) << 3)];
        accO[nb] = __builtin_amdgcn_mfma_f32_16x16x32_bf16(pa, vb, accO[nb], 0, 0, 0);
      }
    }
  }
  // epilogue: /l, write O[(b*T+t)][h*64+dh] bf16
  float lj[4];
#pragma unroll
  for (int j = 0; j < 4; ++j) lj[j] = 1.f / __shfl(l_run, lg * 4 + j);
  int b = hb >> 4, h = hb & 15;
#pragma unroll
  for (int nb = 0; nb < 4; ++nb)
#pragma unroll
    for (int j = 0; j < 4; ++j) {
      int t = q0 + lg * 4 + j;
      O[(size_t)(b * T_ + t) * D_ + h * DH_ + nb * 16 + l15] = f2bf(accO[nb][j] * lj[j]);
    }
}

extern "C" void kernel_launch(void* const* d_in, const int* in_sizes, int n_in,
                              void* d_out, int out_size, void* d_ws, size_t ws_size,
                              hipStream_t stream) {
  const float* x    = (const float*)d_in[0];
  const float* Wqkv = (const float*)d_in[1];
  const float* Wout = (const float*)d_in[2];
  const float* cosT = (const float*)d_in[3];
  const float* sinT = (const float*)d_in[4];
  // d_in[5] = mask (unused; causal handled analytically)
  float* out = (float*)d_out;
  char* ws = (char*)d_ws;
  // ws layout (bytes): 64 MB total
  unsigned short* Xb     = (unsigned short*)(ws);              //  8.0 MB  x bf16 [4096][1024]
  unsigned short* Wqkv_t = (unsigned short*)(ws + 8388608);    //  6.0 MB  Wqkv^T bf16 [3072][1024]
  unsigned short* Wout_t = (unsigned short*)(ws + 14680064);   //  2.0 MB  Wout^T bf16 [1024][1024]
  unsigned short* QKVb   = (unsigned short*)(ws + 16777216);   // 24.0 MB  qkv bf16 [4096][3072]
  unsigned short* Qb     = (unsigned short*)(ws + 41943040);   //  8.0 MB  [BH][T][DH]
  unsigned short* Kb     = (unsigned short*)(ws + 50331648);   //  8.0 MB  [BH][T][DH]
  unsigned short* Vt     = (unsigned short*)(ws + 58720256);   //  8.0 MB  [BH][DH][T]
  unsigned short* Ob     = QKVb;                               // reuse (qkv dead after rope)

  k_cvt<<<4096, 256, 0, stream>>>(x, Xb);
  k_transpose<<<dim3(48, 16), 256, 0, stream>>>(Wqkv, Wqkv_t, 1024, 3072);
  k_transpose<<<dim3(16, 16), 256, 0, stream>>>(Wout, Wout_t, 1024, 1024);
  k_gemm_bt<unsigned short><<<dim3(24, 32), 256, 0, stream>>>(Xb, Wqkv_t, QKVb, 4096, 3072, 1024);
  k_rope<<<8192, 256, 0, stream>>>(QKVb, cosT, sinT, Qb, Kb, Vt);
  k_attn<<<1024, 256, 0, stream>>>(Qb, Kb, Vt, Ob);
  k_gemm_bt<float><<<dim3(8, 32), 256, 0, stream>>>(Ob, Wout_t, out, 4096, 1024, 1024);
}

// Round 6
// 186.388 us; speedup vs baseline: 1.8555x; 1.1383x over previous
//
#include <hip/hip_runtime.h>
#include <hip/hip_bf16.h>

// Fused attention fwd: x@Wqkv -> RoPE -> causal flash attn (bf16 MFMA) -> @Wout
// B=2 T=2048 D=1024 H=16 DH=64
#define B_ 2
#define T_ 2048
#define D_ 1024
#define H_ 16
#define DH_ 64
#define N3_ 3072
#define M_ 4096

typedef __attribute__((ext_vector_type(8))) short short8;      // 8 bf16 (4 VGPR) MFMA A/B frag
typedef __attribute__((ext_vector_type(4))) float f32x4;       // MFMA C/D frag
typedef __attribute__((ext_vector_type(4))) unsigned short ushort4v;

// native f32->bf16 (compiler emits hw cvt; RNE) [m240: scalar cast is the fast path]
__device__ __forceinline__ unsigned short f2bf(float f) {
  return __builtin_bit_cast(unsigned short, __hip_bfloat16(f));
}
__device__ __forceinline__ float bf2f(unsigned short u) {
  union { unsigned u; float f; } v; v.u = ((unsigned)u) << 16;
  return v.f;
}

// async global->LDS, 16B per lane; LDS dest is WAVE-UNIFORM base + lane*16 [m97/m104]
__device__ __forceinline__ void gload_lds16(const unsigned short* g, unsigned short* l) {
  __builtin_amdgcn_global_load_lds((const __attribute__((address_space(1))) void*)g,
                                   (__attribute__((address_space(3))) void*)l, 16, 0, 0);
}

// ---------- f32 -> bf16 bulk convert (4 elems/thread, exact grid) ----------
__global__ __launch_bounds__(256)
void k_cvt(const float* __restrict__ in, unsigned short* __restrict__ out) {
  int i = (blockIdx.x * 256 + threadIdx.x) * 4;
  f32x4 v = *(const f32x4*)&in[i];
  ushort4v o;
  o[0] = f2bf(v[0]); o[1] = f2bf(v[1]); o[2] = f2bf(v[2]); o[3] = f2bf(v[3]);
  *(ushort4v*)&out[i] = o;
}

// ---------- transpose f32 [R][C] -> bf16 [C][R] (64x64 LDS tile) ----------
__global__ __launch_bounds__(256)
void k_transpose(const float* __restrict__ in, unsigned short* __restrict__ out,
                 int R, int C) {
  __shared__ float tile[64][65];
  int c0 = blockIdx.x * 64, r0 = blockIdx.y * 64;
  int tx = threadIdx.x & 63, ty = threadIdx.x >> 6;
#pragma unroll
  for (int i = 0; i < 64; i += 4)
    tile[ty + i][tx] = in[(size_t)(r0 + ty + i) * C + c0 + tx];
  __syncthreads();
#pragma unroll
  for (int i = 0; i < 64; i += 4)
    out[(size_t)(c0 + ty + i) * R + r0 + tx] = f2bf(tile[tx][ty + i]);
}

// ---------- GEMM: C[M][N] = A[M][K] @ Bt[N][K]^T, bf16 in, OUT_T out ----------
// 128x128 tile, BK=64, 4 waves (2x2), 4x4 16x16x32 MFMA frags per wave.
// Staging via global_load_lds width=16 (m97 pattern; linear LDS, no swizzle --
// T2 is null on 2-phase 128^2 [m228d/m230]).
template <typename OUT_T>
__global__ __launch_bounds__(256)
void k_gemm_bt(const unsigned short* __restrict__ A, const unsigned short* __restrict__ Bt,
               OUT_T* __restrict__ C, int Mx, int Nx, int Kx) {
  __shared__ __align__(16) unsigned short As[128 * 64];
  __shared__ __align__(16) unsigned short Bs[128 * 64];
  const int tid = threadIdx.x;
  const int lane = tid & 63;
  const int l15 = lane & 15, lg = lane >> 4;
  const int l8 = lane >> 3, c8 = lane & 7;
  const int wid = tid >> 6;
  const int wr = wid >> 1, wc = wid & 1;
  const int m0 = blockIdx.y * 128, n0 = blockIdx.x * 128;

  const f32x4 zero4 = {0.f, 0.f, 0.f, 0.f};
  f32x4 acc[4][4];
#pragma unroll
  for (int mi = 0; mi < 4; ++mi)
#pragma unroll
    for (int ni = 0; ni < 4; ++ni) acc[mi][ni] = zero4;

  for (int k0 = 0; k0 < Kx; k0 += 64) {
    // wave wid stages rows [wid*32, wid*32+32) of As and Bs; 8 rows per call.
#pragma unroll
    for (int i = 0; i < 4; ++i)
      gload_lds16(&A[(size_t)(m0 + wid * 32 + i * 8 + l8) * Kx + k0 + c8 * 8],
                  &As[(wid * 32 + i * 8) * 64]);
#pragma unroll
    for (int i = 0; i < 4; ++i)
      gload_lds16(&Bt[(size_t)(n0 + wid * 32 + i * 8 + l8) * Kx + k0 + c8 * 8],
                  &Bs[(wid * 32 + i * 8) * 64]);
    __syncthreads();                     // compiler drains vmcnt before barrier
#pragma unroll
    for (int kk = 0; kk < 2; ++kk) {
      short8 af[4], bfr[4];
#pragma unroll
      for (int mi = 0; mi < 4; ++mi)
        af[mi] = *(const short8*)&As[(wr * 64 + mi * 16 + l15) * 64 + kk * 32 + lg * 8];
#pragma unroll
      for (int ni = 0; ni < 4; ++ni)
        bfr[ni] = *(const short8*)&Bs[(wc * 64 + ni * 16 + l15) * 64 + kk * 32 + lg * 8];
#pragma unroll
      for (int mi = 0; mi < 4; ++mi)
#pragma unroll
        for (int ni = 0; ni < 4; ++ni)
          acc[mi][ni] = __builtin_amdgcn_mfma_f32_16x16x32_bf16(af[mi], bfr[ni], acc[mi][ni], 0, 0, 0);
    }
    __syncthreads();
  }
  // C/D layout: reg j -> row (lg*4+j), col l15  [verified m89/m91]
#pragma unroll
  for (int mi = 0; mi < 4; ++mi)
#pragma unroll
    for (int ni = 0; ni < 4; ++ni)
#pragma unroll
      for (int j = 0; j < 4; ++j) {
        int row = m0 + wr * 64 + mi * 16 + lg * 4 + j;
        int col = n0 + wc * 64 + ni * 16 + l15;
        float v = acc[mi][ni][j];
        if constexpr (sizeof(OUT_T) == 2) C[(size_t)row * Nx + col] = f2bf(v);
        else                              C[(size_t)row * Nx + col] = v;
      }
}

// ---------- RoPE + layout: qkv[4096][3072] -> Q,K [BH][T][DH] (Q pre-scaled 1/8), V^T [BH][DH][T] ----------
__global__ __launch_bounds__(256)
void k_rope(const unsigned short* __restrict__ qkv, const float* __restrict__ cosT,
            const float* __restrict__ sinT, unsigned short* __restrict__ Q,
            unsigned short* __restrict__ K, unsigned short* __restrict__ Vt) {
  int idx = blockIdx.x * 256 + threadIdx.x;        // B*H*T*32 threads
  int dh = idx & 31;
  int t  = (idx >> 5) & (T_ - 1);
  int h  = (idx >> 16) & (H_ - 1);
  int b  = idx >> 20;
  size_t base = (size_t)(b * T_ + t) * N3_;
  int c0 = h * DH_ + dh;
  float q1 = bf2f(qkv[base + c0]);
  float q2 = bf2f(qkv[base + c0 + 32]);
  float k1 = bf2f(qkv[base + D_ + c0]);
  float k2 = bf2f(qkv[base + D_ + c0 + 32]);
  float cs = cosT[t * 32 + dh], sn = sinT[t * 32 + dh];
  size_t qkb = ((size_t)(b * H_ + h) * T_ + t) * DH_ + dh;
  Q[qkb]      = f2bf((q1 * cs - q2 * sn) * 0.125f);   // attn scale folded into Q
  Q[qkb + 32] = f2bf((q2 * cs + q1 * sn) * 0.125f);
  K[qkb]      = f2bf(k1 * cs - k2 * sn);
  K[qkb + 32] = f2bf(k2 * cs + k1 * sn);
  size_t vb = ((size_t)(b * H_ + h) * DH_ + dh) * T_ + t;
  Vt[vb]           = qkv[base + 2 * D_ + c0];
  Vt[vb + 32 * T_] = qkv[base + 2 * D_ + c0 + 32];
}

// ---------- causal flash attention (block-cooperative, LDS-staged KV) ----------
// Block = 4 waves x 16 q-rows. KV loop in 64-key tiles, double-buffered LDS staging
// via global_load_lds (linear dest + pre-swizzled global source; reads XOR back).
// ONE softmax round per 64 keys; defer-max (T13, THR=8) skips accO rescale.
__global__ __launch_bounds__(256)
void k_attn(const unsigned short* __restrict__ Q, const unsigned short* __restrict__ K,
            const unsigned short* __restrict__ Vt, unsigned short* __restrict__ O) {
  __shared__ __align__(16) unsigned short Ks[2 * 64 * 64];   // [buf][r][chunk^(r&7)] 8KB/buf
  __shared__ __align__(16) unsigned short Vs[2 * 64 * 64];   // same, rows = dh
  __shared__ __align__(16) unsigned short Pl[4][16][72];     // per-wave P tile (64 + pad 8)
  const int tid = threadIdx.x;
  const int wid = tid >> 6, lane = tid & 63;
  const int l15 = lane & 15, lg = lane >> 4;
  const int l8 = lane >> 3, c8 = lane & 7;
  const int srcoff = (c8 ^ l8) << 3;          // swizzled source chunk (ushort units)
  const int qb = 31 - (blockIdx.x & 31);      // reversed: longest jobs first
  const int hb = blockIdx.x >> 5;             // b*H + h
  const int qblk = qb * 64;
  const int q0 = qblk + wid * 16;
  const size_t hbase = (size_t)hb * T_ * DH_;
  const unsigned short* Qh = Q + hbase;
  const unsigned short* Kh = K + hbase;
  const unsigned short* Vh = Vt + hbase;      // [DH][T]
  unsigned short* Pw = &Pl[wid][0][0];

  // Q^T B-frags, hoisted (b[i] = Q[q0+l15][kk*32+lg*8+i])
  short8 bq0 = *(const short8*)&Qh[(q0 + l15) * DH_ + lg * 8];
  short8 bq1 = *(const short8*)&Qh[(q0 + l15) * DH_ + 32 + lg * 8];

  const f32x4 zero4 = {0.f, 0.f, 0.f, 0.f};
  f32x4 accO[4];
#pragma unroll
  for (int nb = 0; nb < 4; ++nb) accO[nb] = zero4;
  float m_run = -INFINITY, l_run = 0.f;
  const int qg = q0 + l15;
  const int kend_w = q0 + 16;                 // wave's exclusive key bound
  const int kend_blk = qblk + 64;             // block's exclusive key bound

  // stage one 64-key K+V tile: LDS[r][c] = X[r][c^(r&7)] (both-sides swizzle)
  auto stage = [&](int buf, int kt) {
    if (wid < 2) {
#pragma unroll
      for (int i = 0; i < 4; ++i) {
        int ch = wid * 4 + i;
        gload_lds16(&Kh[(size_t)(kt + ch * 8 + l8) * DH_ + srcoff],
                    &Ks[buf * 4096 + ch * 512]);
      }
    } else {
#pragma unroll
      for (int i = 0; i < 4; ++i) {
        int ch = (wid - 2) * 4 + i;
        gload_lds16(&Vh[(size_t)(ch * 8 + l8) * T_ + kt + srcoff],
                    &Vs[buf * 4096 + ch * 512]);
      }
    }
  };

  stage(0, 0);
  for (int kt = 0; kt < kend_blk; kt += 64) {
    const int cur = (kt >> 6) & 1;
    __syncthreads();                          // staging of cur landed; cur^1 free
    if (kt + 64 < kend_blk) stage(cur ^ 1, kt + 64);
    if (kt >= kend_w) continue;               // wave-uniform; keeps hitting barrier
    const unsigned short* Kb_ = &Ks[cur * 4096];
    const unsigned short* Vb_ = &Vs[cur * 4096];

    // S^T: 4 k-groups of 16 rows; lane holds S[q=q0+l15][k=kt+g*16+lg*4+j]
    f32x4 cg[4];
#pragma unroll
    for (int g = 0; g < 4; ++g) {
      int r = g * 16 + l15;
      short8 a0 = *(const short8*)&Kb_[r * 64 + (((lg)     ^ (r & 7)) << 3)];
      short8 a1 = *(const short8*)&Kb_[r * 64 + (((4 + lg) ^ (r & 7)) << 3)];
      cg[g] = __builtin_amdgcn_mfma_f32_16x16x32_bf16(a0, bq0, zero4, 0, 0, 0);
      cg[g] = __builtin_amdgcn_mfma_f32_16x16x32_bf16(a1, bq1, cg[g], 0, 0, 0);
    }
    float s[16];
#pragma unroll
    for (int g = 0; g < 4; ++g)
#pragma unroll
      for (int j = 0; j < 4; ++j) s[g * 4 + j] = cg[g][j];
    if (kt + 63 > q0) {                       // boundary tile: causal mask
#pragma unroll
      for (int g = 0; g < 4; ++g) {
        int kb0 = kt + g * 16 + lg * 4;
#pragma unroll
        for (int j = 0; j < 4; ++j)
          if (kb0 + j > qg) s[g * 4 + j] = -INFINITY;
      }
    }
    float pm = s[0];
#pragma unroll
    for (int j = 1; j < 16; ++j) pm = fmaxf(pm, s[j]);
    pm = fmaxf(pm, __shfl_xor(pm, 16));
    pm = fmaxf(pm, __shfl_xor(pm, 32));
    // defer-max [T13]: only rescale when the running max grew by > 8
    if (!__all(pm <= m_run + 8.f)) {
      float m_new = fmaxf(m_run, pm);
      float alpha = __expf(m_run - m_new);    // first tile: exp(-inf)=0
      float aj[4];
#pragma unroll
      for (int j = 0; j < 4; ++j) aj[j] = __shfl(alpha, lg * 4 + j);
#pragma unroll
      for (int nb = 0; nb < 4; ++nb)
#pragma unroll
        for (int j = 0; j < 4; ++j) accO[nb][j] *= aj[j];
      l_run *= alpha;
      m_run = m_new;
    }
    float p[16], psum = 0.f;
#pragma unroll
    for (int j = 0; j < 16; ++j) { p[j] = __expf(s[j] - m_run); psum += p[j]; }
    psum += __shfl_xor(psum, 16);
    psum += __shfl_xor(psum, 32);
    l_run += psum;

    // P -> LDS (bf16), 4x 8B stores at P[q=l15][g*16+lg*4]
#pragma unroll
    for (int g = 0; g < 4; ++g) {
      ushort4v pk;
#pragma unroll
      for (int j = 0; j < 4; ++j) pk[j] = f2bf(p[g * 4 + j]);
      *(ushort4v*)&Pw[l15 * 72 + g * 16 + lg * 4] = pk;
    }
    // PV: A-frag from LDS P, B-frag from swizzled V tile (rows = dh)
#pragma unroll
    for (int ks = 0; ks < 2; ++ks) {
      short8 pa = *(const short8*)&Pw[l15 * 72 + ks * 32 + lg * 8];
#pragma unroll
      for (int nb = 0; nb < 4; ++nb) {
        int r = nb * 16 + l15;
        short8 vb = *(const short8*)&Vb_[r * 64 + (((ks * 4 + lg) ^ (r & 7)) << 3)];
        accO[nb] = __builtin_amdgcn_mfma_f32_16x16x32_bf16(pa, vb, accO[nb], 0, 0, 0);
      }
    }
  }
  // epilogue: /l, write O[(b*T+t)][h*64+dh] bf16
  float lj[4];
#pragma unroll
  for (int j = 0; j < 4; ++j) lj[j] = 1.f / __shfl(l_run, lg * 4 + j);
  int b = hb >> 4, h = hb & 15;
#pragma unroll
  for (int nb = 0; nb < 4; ++nb)
#pragma unroll
    for (int j = 0; j < 4; ++j) {
      int t = q0 + lg * 4 + j;
      O[(size_t)(b * T_ + t) * D_ + h * DH_ + nb * 16 + l15] = f2bf(accO[nb][j] * lj[j]);
    }
}

extern "C" void kernel_launch(void* const* d_in, const int* in_sizes, int n_in,
                              void* d_out, int out_size, void* d_ws, size_t ws_size,
                              hipStream_t stream) {
  const float* x    = (const float*)d_in[0];
  const float* Wqkv = (const float*)d_in[1];
  const float* Wout = (const float*)d_in[2];
  const float* cosT = (const float*)d_in[3];
  const float* sinT = (const float*)d_in[4];
  // d_in[5] = mask (unused; causal handled analytically)
  float* out = (float*)d_out;
  char* ws = (char*)d_ws;
  // ws layout (bytes): 64 MB total
  unsigned short* Xb     = (unsigned short*)(ws);              //  8.0 MB  x bf16 [4096][1024]
  unsigned short* Wqkv_t = (unsigned short*)(ws + 8388608);    //  6.0 MB  Wqkv^T bf16 [3072][1024]
  unsigned short* Wout_t = (unsigned short*)(ws + 14680064);   //  2.0 MB  Wout^T bf16 [1024][1024]
  unsigned short* QKVb   = (unsigned short*)(ws + 16777216);   // 24.0 MB  qkv bf16 [4096][3072]
  unsigned short* Qb     = (unsigned short*)(ws + 41943040);   //  8.0 MB  [BH][T][DH]
  unsigned short* Kb     = (unsigned short*)(ws + 50331648);   //  8.0 MB  [BH][T][DH]
  unsigned short* Vt     = (unsigned short*)(ws + 58720256);   //  8.0 MB  [BH][DH][T]
  unsigned short* Ob     = QKVb;                               // reuse (qkv dead after rope)

  k_cvt<<<4096, 256, 0, stream>>>(x, Xb);
  k_transpose<<<dim3(48, 16), 256, 0, stream>>>(Wqkv, Wqkv_t, 1024, 3072);
  k_transpose<<<dim3(16, 16), 256, 0, stream>>>(Wout, Wout_t, 1024, 1024);
  k_gemm_bt<unsigned short><<<dim3(24, 32), 256, 0, stream>>>(Xb, Wqkv_t, QKVb, 4096, 3072, 1024);
  k_rope<<<8192, 256, 0, stream>>>(QKVb, cosT, sinT, Qb, Kb, Vt);
  k_attn<<<1024, 256, 0, stream>>>(Qb, Kb, Vt, Ob);
  k_gemm_bt<float><<<dim3(8, 32), 256, 0, stream>>>(Ob, Wout_t, out, 4096, 1024, 1024);
}

// Round 7
// 164.342 us; speedup vs baseline: 2.1044x; 1.1341x over previous
//
#include <hip/hip_runtime.h>
#include <hip/hip_bf16.h>

// Fused attention fwd: x@Wqkv -> RoPE -> causal flash attn (bf16 MFMA) -> @Wout
// B=2 T=2048 D=1024 H=16 DH=64
#define B_ 2
#define T_ 2048
#define D_ 1024
#define H_ 16
#define DH_ 64
#define N3_ 3072
#define M_ 4096

typedef __attribute__((ext_vector_type(8))) short short8;      // 8 bf16 (4 VGPR) MFMA A/B frag
typedef __attribute__((ext_vector_type(4))) float f32x4;       // MFMA C/D frag
typedef __attribute__((ext_vector_type(4))) unsigned short ushort4v;

// native f32->bf16 (compiler emits hw cvt; RNE) [m240: scalar cast is the fast path]
__device__ __forceinline__ unsigned short f2bf(float f) {
  return __builtin_bit_cast(unsigned short, __hip_bfloat16(f));
}
__device__ __forceinline__ float bf2f(unsigned short u) {
  union { unsigned u; float f; } v; v.u = ((unsigned)u) << 16;
  return v.f;
}

// async global->LDS, 16B per lane; LDS dest is WAVE-UNIFORM base + lane*16 [m97/m104]
__device__ __forceinline__ void gload_lds16(const unsigned short* g, unsigned short* l) {
  __builtin_amdgcn_global_load_lds((const __attribute__((address_space(1))) void*)g,
                                   (__attribute__((address_space(3))) void*)l, 16, 0, 0);
}

// ---------- f32 -> bf16 bulk convert (4 elems/thread, exact grid) ----------
__global__ __launch_bounds__(256)
void k_cvt(const float* __restrict__ in, unsigned short* __restrict__ out) {
  int i = (blockIdx.x * 256 + threadIdx.x) * 4;
  f32x4 v = *(const f32x4*)&in[i];
  ushort4v o;
  o[0] = f2bf(v[0]); o[1] = f2bf(v[1]); o[2] = f2bf(v[2]); o[3] = f2bf(v[3]);
  *(ushort4v*)&out[i] = o;
}

// ---------- transpose f32 [R][C] -> bf16 [C][R] (64x64 LDS tile) ----------
__global__ __launch_bounds__(256)
void k_transpose(const float* __restrict__ in, unsigned short* __restrict__ out,
                 int R, int C) {
  __shared__ float tile[64][65];
  int c0 = blockIdx.x * 64, r0 = blockIdx.y * 64;
  int tx = threadIdx.x & 63, ty = threadIdx.x >> 6;
#pragma unroll
  for (int i = 0; i < 64; i += 4)
    tile[ty + i][tx] = in[(size_t)(r0 + ty + i) * C + c0 + tx];
  __syncthreads();
#pragma unroll
  for (int i = 0; i < 64; i += 4)
    out[(size_t)(c0 + ty + i) * R + r0 + tx] = f2bf(tile[tx][ty + i]);
}

// ---------- GEMM: C[M][N] = A[M][K] @ Bt[N][K]^T, bf16 in, OUT_T out ----------
// 128x128 tile, BK=64, 4 waves (2x2), 4x4 16x16x32 MFMA frags per wave.
// Staging via global_load_lds width=16 (m97 pattern; linear LDS, no swizzle --
// T2 is null on 2-phase 128^2 [m228d/m230]).
template <typename OUT_T>
__global__ __launch_bounds__(256)
void k_gemm_bt(const unsigned short* __restrict__ A, const unsigned short* __restrict__ Bt,
               OUT_T* __restrict__ C, int Mx, int Nx, int Kx) {
  __shared__ __align__(16) unsigned short As[128 * 64];
  __shared__ __align__(16) unsigned short Bs[128 * 64];
  const int tid = threadIdx.x;
  const int lane = tid & 63;
  const int l15 = lane & 15, lg = lane >> 4;
  const int l8 = lane >> 3, c8 = lane & 7;
  const int wid = tid >> 6;
  const int wr = wid >> 1, wc = wid & 1;
  const int m0 = blockIdx.y * 128, n0 = blockIdx.x * 128;

  const f32x4 zero4 = {0.f, 0.f, 0.f, 0.f};
  f32x4 acc[4][4];
#pragma unroll
  for (int mi = 0; mi < 4; ++mi)
#pragma unroll
    for (int ni = 0; ni < 4; ++ni) acc[mi][ni] = zero4;

  for (int k0 = 0; k0 < Kx; k0 += 64) {
    // wave wid stages rows [wid*32, wid*32+32) of As and Bs; 8 rows per call.
#pragma unroll
    for (int i = 0; i < 4; ++i)
      gload_lds16(&A[(size_t)(m0 + wid * 32 + i * 8 + l8) * Kx + k0 + c8 * 8],
                  &As[(wid * 32 + i * 8) * 64]);
#pragma unroll
    for (int i = 0; i < 4; ++i)
      gload_lds16(&Bt[(size_t)(n0 + wid * 32 + i * 8 + l8) * Kx + k0 + c8 * 8],
                  &Bs[(wid * 32 + i * 8) * 64]);
    __syncthreads();                     // compiler drains vmcnt before barrier
#pragma unroll
    for (int kk = 0; kk < 2; ++kk) {
      short8 af[4], bfr[4];
#pragma unroll
      for (int mi = 0; mi < 4; ++mi)
        af[mi] = *(const short8*)&As[(wr * 64 + mi * 16 + l15) * 64 + kk * 32 + lg * 8];
#pragma unroll
      for (int ni = 0; ni < 4; ++ni)
        bfr[ni] = *(const short8*)&Bs[(wc * 64 + ni * 16 + l15) * 64 + kk * 32 + lg * 8];
#pragma unroll
      for (int mi = 0; mi < 4; ++mi)
#pragma unroll
        for (int ni = 0; ni < 4; ++ni)
          acc[mi][ni] = __builtin_amdgcn_mfma_f32_16x16x32_bf16(af[mi], bfr[ni], acc[mi][ni], 0, 0, 0);
    }
    __syncthreads();
  }
  // C/D layout: reg j -> row (lg*4+j), col l15  [verified m89/m91]
#pragma unroll
  for (int mi = 0; mi < 4; ++mi)
#pragma unroll
    for (int ni = 0; ni < 4; ++ni)
#pragma unroll
      for (int j = 0; j < 4; ++j) {
        int row = m0 + wr * 64 + mi * 16 + lg * 4 + j;
        int col = n0 + wc * 64 + ni * 16 + l15;
        float v = acc[mi][ni][j];
        if constexpr (sizeof(OUT_T) == 2) C[(size_t)row * Nx + col] = f2bf(v);
        else                              C[(size_t)row * Nx + col] = v;
      }
}

// ---------- RoPE + layout: qkv[4096][3072] -> Q,K [BH][T][DH] (Q pre-scaled 1/8), V^T [BH][DH][T] ----------
__global__ __launch_bounds__(256)
void k_rope(const unsigned short* __restrict__ qkv, const float* __restrict__ cosT,
            const float* __restrict__ sinT, unsigned short* __restrict__ Q,
            unsigned short* __restrict__ K, unsigned short* __restrict__ Vt) {
  int idx = blockIdx.x * 256 + threadIdx.x;        // B*H*T*32 threads
  int dh = idx & 31;
  int t  = (idx >> 5) & (T_ - 1);
  int h  = (idx >> 16) & (H_ - 1);
  int b  = idx >> 20;
  size_t base = (size_t)(b * T_ + t) * N3_;
  int c0 = h * DH_ + dh;
  float q1 = bf2f(qkv[base + c0]);
  float q2 = bf2f(qkv[base + c0 + 32]);
  float k1 = bf2f(qkv[base + D_ + c0]);
  float k2 = bf2f(qkv[base + D_ + c0 + 32]);
  float cs = cosT[t * 32 + dh], sn = sinT[t * 32 + dh];
  size_t qkb = ((size_t)(b * H_ + h) * T_ + t) * DH_ + dh;
  Q[qkb]      = f2bf((q1 * cs - q2 * sn) * 0.125f);   // attn scale folded into Q
  Q[qkb + 32] = f2bf((q2 * cs + q1 * sn) * 0.125f);
  K[qkb]      = f2bf(k1 * cs - k2 * sn);
  K[qkb + 32] = f2bf(k2 * cs + k1 * sn);
  size_t vb = ((size_t)(b * H_ + h) * DH_ + dh) * T_ + t;
  Vt[vb]           = qkv[base + 2 * D_ + c0];
  Vt[vb + 32 * T_] = qkv[base + 2 * D_ + c0 + 32];
}

// ---------- causal flash attention (block-cooperative, LDS-staged KV) ----------
// Block = 4 waves x 16 q-rows. KV loop in 64-key tiles, double-buffered LDS staging
// via global_load_lds (linear dest + pre-swizzled global source; reads XOR back).
// ONE softmax round per 64 keys; defer-max (T13, THR=8) skips accO rescale.
// XCD-chunked block swizzle [T1/m204]: each XCD owns 4 heads -> K/V L2-resident.
__global__ __launch_bounds__(256)
void k_attn(const unsigned short* __restrict__ Q, const unsigned short* __restrict__ K,
            const unsigned short* __restrict__ Vt, unsigned short* __restrict__ O) {
  __shared__ __align__(16) unsigned short Ks[2 * 64 * 64];   // [buf][r][chunk^(r&7)] 8KB/buf
  __shared__ __align__(16) unsigned short Vs[2 * 64 * 64];   // same, rows = dh
  __shared__ __align__(16) unsigned short Pl[4][16][72];     // per-wave P tile (64 + pad 8)
  const int tid = threadIdx.x;
  const int wid = tid >> 6, lane = tid & 63;
  const int l15 = lane & 15, lg = lane >> 4;
  const int l8 = lane >> 3, c8 = lane & 7;
  const int srcoff = (c8 ^ l8) << 3;          // swizzled source chunk (ushort units)
  // XCD-chunked bijective swizzle (nwg=1024, 8 XCDs, 128 blocks per XCD):
  // XCD i gets logical blocks [i*128,(i+1)*128) = heads 4i..4i+3 (2MB K/V < 4MB L2).
  const int wg = (blockIdx.x & 7) * 128 + (blockIdx.x >> 3);
  const int qb = 31 - (wg & 31);              // reversed: longest jobs first
  const int hb = wg >> 5;                     // b*H + h
  const int qblk = qb * 64;
  const int q0 = qblk + wid * 16;
  const size_t hbase = (size_t)hb * T_ * DH_;
  const unsigned short* Qh = Q + hbase;
  const unsigned short* Kh = K + hbase;
  const unsigned short* Vh = Vt + hbase;      // [DH][T]
  unsigned short* Pw = &Pl[wid][0][0];

  // Q^T B-frags, hoisted (b[i] = Q[q0+l15][kk*32+lg*8+i])
  short8 bq0 = *(const short8*)&Qh[(q0 + l15) * DH_ + lg * 8];
  short8 bq1 = *(const short8*)&Qh[(q0 + l15) * DH_ + 32 + lg * 8];

  // hoisted swizzled LDS read offsets (kt-invariant; unrolled-const indexed)
  int koffA[4], koffB[4], voff[2][4];
#pragma unroll
  for (int g = 0; g < 4; ++g) {
    int r = g * 16 + l15;
    koffA[g] = r * 64 + (((lg)     ^ (r & 7)) << 3);
    koffB[g] = r * 64 + (((4 + lg) ^ (r & 7)) << 3);
  }
#pragma unroll
  for (int ks = 0; ks < 2; ++ks)
#pragma unroll
    for (int nb = 0; nb < 4; ++nb) {
      int r = nb * 16 + l15;
      voff[ks][nb] = r * 64 + (((ks * 4 + lg) ^ (r & 7)) << 3);
    }

  const f32x4 zero4 = {0.f, 0.f, 0.f, 0.f};
  f32x4 accO[4];
#pragma unroll
  for (int nb = 0; nb < 4; ++nb) accO[nb] = zero4;
  float m_run = -INFINITY, l_run = 0.f;
  const int qg = q0 + l15;
  const int kend_w = q0 + 16;                 // wave's exclusive key bound
  const int kend_blk = qblk + 64;             // block's exclusive key bound

  // stage one 64-key K+V tile: LDS[r][c] = X[r][c^(r&7)] (both-sides swizzle)
  auto stage = [&](int buf, int kt) {
    if (wid < 2) {
      const unsigned short* Kt = Kh + (size_t)kt * DH_;
#pragma unroll
      for (int i = 0; i < 4; ++i)
        gload_lds16(&Kt[(wid * 32 + i * 8 + l8) * DH_ + srcoff],
                    &Ks[buf * 4096 + (wid * 4 + i) * 512]);
    } else {
      const unsigned short* Vg = Vh + kt;
#pragma unroll
      for (int i = 0; i < 4; ++i)
        gload_lds16(&Vg[((wid - 2) * 32 + i * 8 + l8) * T_ + srcoff],
                    &Vs[buf * 4096 + ((wid - 2) * 4 + i) * 512]);
    }
  };

  stage(0, 0);
  for (int kt = 0; kt < kend_blk; kt += 64) {
    const int cur = (kt >> 6) & 1;
    __syncthreads();                          // staging of cur landed; cur^1 free
    if (kt + 64 < kend_blk) stage(cur ^ 1, kt + 64);
    if (kt >= kend_w) continue;               // wave-uniform; keeps hitting barrier
    const unsigned short* Kb_ = &Ks[cur * 4096];
    const unsigned short* Vb_ = &Vs[cur * 4096];

    // S^T: 4 k-groups of 16 rows; lane holds S[q=q0+l15][k=kt+g*16+lg*4+j]
    f32x4 cg[4];
#pragma unroll
    for (int g = 0; g < 4; ++g) {
      short8 a0 = *(const short8*)&Kb_[koffA[g]];
      short8 a1 = *(const short8*)&Kb_[koffB[g]];
      cg[g] = __builtin_amdgcn_mfma_f32_16x16x32_bf16(a0, bq0, zero4, 0, 0, 0);
      cg[g] = __builtin_amdgcn_mfma_f32_16x16x32_bf16(a1, bq1, cg[g], 0, 0, 0);
    }
    float s[16];
#pragma unroll
    for (int g = 0; g < 4; ++g)
#pragma unroll
      for (int j = 0; j < 4; ++j) s[g * 4 + j] = cg[g][j];
    if (kt + 63 > q0) {                       // boundary tile: causal mask
#pragma unroll
      for (int g = 0; g < 4; ++g) {
        int kb0 = kt + g * 16 + lg * 4;
#pragma unroll
        for (int j = 0; j < 4; ++j)
          if (kb0 + j > qg) s[g * 4 + j] = -INFINITY;
      }
    }
    // tree max (depth 4, not 15-deep chain)
    float t8[8];
#pragma unroll
    for (int j = 0; j < 8; ++j) t8[j] = fmaxf(s[j], s[j + 8]);
    float t4a = fmaxf(t8[0], t8[4]), t4b = fmaxf(t8[1], t8[5]);
    float t4c = fmaxf(t8[2], t8[6]), t4d = fmaxf(t8[3], t8[7]);
    float pm = fmaxf(fmaxf(t4a, t4b), fmaxf(t4c, t4d));
    pm = fmaxf(pm, __shfl_xor(pm, 16));
    pm = fmaxf(pm, __shfl_xor(pm, 32));
    // defer-max [T13]: only rescale when the running max grew by > 8
    if (!__all(pm <= m_run + 8.f)) {
      float m_new = fmaxf(m_run, pm);
      float alpha = __expf(m_run - m_new);    // first tile: exp(-inf)=0
      float aj[4];
#pragma unroll
      for (int j = 0; j < 4; ++j) aj[j] = __shfl(alpha, lg * 4 + j);
#pragma unroll
      for (int nb = 0; nb < 4; ++nb)
#pragma unroll
        for (int j = 0; j < 4; ++j) accO[nb][j] *= aj[j];
      l_run *= alpha;
      m_run = m_new;
    }
    float p[16];
#pragma unroll
    for (int j = 0; j < 16; ++j) p[j] = __expf(s[j] - m_run);
    // tree sum
    float u8[8];
#pragma unroll
    for (int j = 0; j < 8; ++j) u8[j] = p[j] + p[j + 8];
    float u4a = u8[0] + u8[4], u4b = u8[1] + u8[5];
    float u4c = u8[2] + u8[6], u4d = u8[3] + u8[7];
    float psum = (u4a + u4b) + (u4c + u4d);
    psum += __shfl_xor(psum, 16);
    psum += __shfl_xor(psum, 32);
    l_run += psum;

    // P -> LDS (bf16), 4x 8B stores at P[q=l15][g*16+lg*4]
#pragma unroll
    for (int g = 0; g < 4; ++g) {
      ushort4v pk;
#pragma unroll
      for (int j = 0; j < 4; ++j) pk[j] = f2bf(p[g * 4 + j]);
      *(ushort4v*)&Pw[l15 * 72 + g * 16 + lg * 4] = pk;
    }
    // PV: A-frag from LDS P, B-frag from swizzled V tile (rows = dh)
#pragma unroll
    for (int ks = 0; ks < 2; ++ks) {
      short8 pa = *(const short8*)&Pw[l15 * 72 + ks * 32 + lg * 8];
#pragma unroll
      for (int nb = 0; nb < 4; ++nb) {
        short8 vb = *(const short8*)&Vb_[voff[ks][nb]];
        accO[nb] = __builtin_amdgcn_mfma_f32_16x16x32_bf16(pa, vb, accO[nb], 0, 0, 0);
      }
    }
  }
  // epilogue: /l, write O[(b*T+t)][h*64+dh] bf16
  float lj[4];
#pragma unroll
  for (int j = 0; j < 4; ++j) lj[j] = 1.f / __shfl(l_run, lg * 4 + j);
  int b = hb >> 4, h = hb & 15;
#pragma unroll
  for (int nb = 0; nb < 4; ++nb)
#pragma unroll
    for (int j = 0; j < 4; ++j) {
      int t = q0 + lg * 4 + j;
      O[(size_t)(b * T_ + t) * D_ + h * DH_ + nb * 16 + l15] = f2bf(accO[nb][j] * lj[j]);
    }
}

extern "C" void kernel_launch(void* const* d_in, const int* in_sizes, int n_in,
                              void* d_out, int out_size, void* d_ws, size_t ws_size,
                              hipStream_t stream) {
  const float* x    = (const float*)d_in[0];
  const float* Wqkv = (const float*)d_in[1];
  const float* Wout = (const float*)d_in[2];
  const float* cosT = (const float*)d_in[3];
  const float* sinT = (const float*)d_in[4];
  // d_in[5] = mask (unused; causal handled analytically)
  float* out = (float*)d_out;
  char* ws = (char*)d_ws;
  // ws layout (bytes): 64 MB total
  unsigned short* Xb     = (unsigned short*)(ws);              //  8.0 MB  x bf16 [4096][1024]
  unsigned short* Wqkv_t = (unsigned short*)(ws + 8388608);    //  6.0 MB  Wqkv^T bf16 [3072][1024]
  unsigned short* Wout_t = (unsigned short*)(ws + 14680064);   //  2.0 MB  Wout^T bf16 [1024][1024]
  unsigned short* QKVb   = (unsigned short*)(ws + 16777216);   // 24.0 MB  qkv bf16 [4096][3072]
  unsigned short* Qb     = (unsigned short*)(ws + 41943040);   //  8.0 MB  [BH][T][DH]
  unsigned short* Kb     = (unsigned short*)(ws + 50331648);   //  8.0 MB  [BH][T][DH]
  unsigned short* Vt     = (unsigned short*)(ws + 58720256);   //  8.0 MB  [BH][DH][T]
  unsigned short* Ob     = QKVb;                               // reuse (qkv dead after rope)

  k_cvt<<<4096, 256, 0, stream>>>(x, Xb);
  k_transpose<<<dim3(48, 16), 256, 0, stream>>>(Wqkv, Wqkv_t, 1024, 3072);
  k_transpose<<<dim3(16, 16), 256, 0, stream>>>(Wout, Wout_t, 1024, 1024);
  k_gemm_bt<unsigned short><<<dim3(24, 32), 256, 0, stream>>>(Xb, Wqkv_t, QKVb, 4096, 3072, 1024);
  k_rope<<<8192, 256, 0, stream>>>(QKVb, cosT, sinT, Qb, Kb, Vt);
  k_attn<<<1024, 256, 0, stream>>>(Qb, Kb, Vt, Ob);
  k_gemm_bt<float><<<dim3(8, 32), 256, 0, stream>>>(Ob, Wout_t, out, 4096, 1024, 1024);
}